// Round 4
// baseline (8945.767 us; speedup 1.0000x reference)
//
#include <hip/hip_runtime.h>
#include <stdint.h>

typedef unsigned long long u64;

#define NBATCH 32
#define NPTS   131072
#define KBLK   8                 // blocks per batch
#define PPB    16384             // points per block
#define NTHR   1024
#define NWAVE  16
#define PPT    16                // points per thread
#define FLT_MAX_C 3.402823466e+38f

// ws: per (batch, block, parity) one 64B slot of 8 u64.
// words 0..2: ((u64)s<<32) | float_bits(x|y|z)   -- self-tagged, relaxed
// word  3   : ((u64)s<<49) | dist_bits<<17 | (131071-gidx)
//   dist>=0 -> float bits monotone as uint; idx inverted so u64-max gives
//   first-occurrence argmax (np.argmax tie-break). 0xAA poison / stale tags
//   never equal live s -> no ws init needed; parity double-buffer + skew<=1.
__device__ __forceinline__ u64* slot_ptr(u64* slots, int b, int k, int par) {
    return slots + ((size_t)((b * KBLK + k) * 2 + par)) * 8;
}

__global__ __launch_bounds__(NTHR, 4)
void fps_kernel(const float* __restrict__ points, int* __restrict__ out,
                u64* __restrict__ slots, int S)
{
    const int b    = blockIdx.x & (NBATCH - 1);
    const int kk   = blockIdx.x >> 5;
    const int t    = threadIdx.x;
    const int lane = t & 63;
    const int wv   = t >> 6;

    const float* pb = points + (size_t)b * 3 * NPTS;
    const float* bx = pb + kk * PPB;
    const float* by = bx + NPTS;
    const float* bz = bx + 2 * NPTS;

    // 12 of 16 per-thread min-dists live in LDS (private slot per thread:
    // no sharing, no barrier, b128 16B/lane access = conflict-free).
    __shared__ float4 s_md[3][NTHR];                       // 48 KB
    __shared__ float s_pv[NWAVE], s_px[NWAVE], s_py[NWAVE], s_pz[NWAVE];
    __shared__ int   s_pi[NWAVE];
    __shared__ unsigned s_bc[3];

    float px[PPT], py[PPT], pz[PPT];   // read-only coords: 48 VGPRs
    float4 mdr;                        // group c=3 min-dist in registers
    const int t4 = t * 4;

#pragma unroll
    for (int c = 0; c < 4; ++c) {
        float4 vx = *(const float4*)(bx + c * (NTHR * 4) + t4);
        float4 vy = *(const float4*)(by + c * (NTHR * 4) + t4);
        float4 vz = *(const float4*)(bz + c * (NTHR * 4) + t4);
        px[c*4+0]=vx.x; px[c*4+1]=vx.y; px[c*4+2]=vx.z; px[c*4+3]=vx.w;
        py[c*4+0]=vy.x; py[c*4+1]=vy.y; py[c*4+2]=vy.z; py[c*4+3]=vy.w;
        pz[c*4+0]=vz.x; pz[c*4+1]=vz.y; pz[c*4+2]=vz.z; pz[c*4+3]=vz.w;
    }
    {
        float4 f4 = make_float4(FLT_MAX_C, FLT_MAX_C, FLT_MAX_C, FLT_MAX_C);
        s_md[0][t] = f4; s_md[1][t] = f4; s_md[2][t] = f4; mdr = f4;
    }

    float cx = pb[0], cy = pb[NPTS], cz = pb[2 * NPTS];
    if (kk == 0 && t == 0) out[(size_t)b * S] = 0;

    for (int s = 1; s < S; ++s) {
        // ---- scan: exact np fp32 semantics (no fma), ascending index, '>'
        float bv = -1.0f; int bix = 0;
        float bwx = 0.f, bwy = 0.f, bwz = 0.f;
#define SCAN1(PXV, PYV, PZV, MREF, IDXC)                                    \
        {                                                                   \
            float dx = __fsub_rn(PXV, cx);                                  \
            float dy = __fsub_rn(PYV, cy);                                  \
            float dz = __fsub_rn(PZV, cz);                                  \
            float d  = __fadd_rn(__fadd_rn(__fmul_rn(dx, dx),               \
                                           __fmul_rn(dy, dy)),              \
                                 __fmul_rn(dz, dz));                        \
            float m  = fminf(MREF, d);                                      \
            MREF = m;                                                       \
            bool tk = m > bv;                                               \
            bv  = tk ? m : bv;                                              \
            bix = tk ? (IDXC) : bix;                                        \
            bwx = tk ? (PXV) : bwx;                                         \
            bwy = tk ? (PYV) : bwy;                                         \
            bwz = tk ? (PZV) : bwz;                                         \
        }
#pragma unroll
        for (int c = 0; c < 3; ++c) {
            float4 m4 = s_md[c][t];                    // ds_read_b128
            SCAN1(px[c*4+0], py[c*4+0], pz[c*4+0], m4.x, c*4096 + t4 + 0);
            SCAN1(px[c*4+1], py[c*4+1], pz[c*4+1], m4.y, c*4096 + t4 + 1);
            SCAN1(px[c*4+2], py[c*4+2], pz[c*4+2], m4.z, c*4096 + t4 + 2);
            SCAN1(px[c*4+3], py[c*4+3], pz[c*4+3], m4.w, c*4096 + t4 + 3);
            s_md[c][t] = m4;                           // ds_write_b128
        }
        SCAN1(px[12], py[12], pz[12], mdr.x, 12288 + t4 + 0);
        SCAN1(px[13], py[13], pz[13], mdr.y, 12288 + t4 + 1);
        SCAN1(px[14], py[14], pz[14], mdr.z, 12288 + t4 + 2);
        SCAN1(px[15], py[15], pz[15], mdr.w, 12288 + t4 + 3);
#undef SCAN1

        // ---- wave reduce carrying coords, tie -> lower index
#pragma unroll
        for (int off = 32; off >= 1; off >>= 1) {
            float ov = __shfl_down(bv, off);
            int   oi = __shfl_down(bix, off);
            float ox = __shfl_down(bwx, off);
            float oy = __shfl_down(bwy, off);
            float oz = __shfl_down(bwz, off);
            bool tk = (ov > bv) || (ov == bv && oi < bix);
            bv  = tk ? ov : bv;
            bix = tk ? oi : bix;
            bwx = tk ? ox : bwx;
            bwy = tk ? oy : bwy;
            bwz = tk ? oz : bwz;
        }
        if (lane == 0) {
            s_pv[wv] = bv; s_pi[wv] = bix;
            s_px[wv] = bwx; s_py[wv] = bwy; s_pz[wv] = bwz;
        }
        __syncthreads();   // barrier 1: partials ready

        if (wv == 0) {
            // cross-wave reduce over 16 partials
            float v16 = (lane < NWAVE) ? s_pv[lane] : -1.0f;
            int   i16 = (lane < NWAVE) ? s_pi[lane] : 0x7fffffff;
            float x16 = (lane < NWAVE) ? s_px[lane] : 0.f;
            float y16 = (lane < NWAVE) ? s_py[lane] : 0.f;
            float z16 = (lane < NWAVE) ? s_pz[lane] : 0.f;
#pragma unroll
            for (int off = 8; off >= 1; off >>= 1) {
                float ov = __shfl_down(v16, off);
                int   oi = __shfl_down(i16, off);
                float ox = __shfl_down(x16, off);
                float oy = __shfl_down(y16, off);
                float oz = __shfl_down(z16, off);
                bool tk = (ov > v16) || (ov == v16 && oi < i16);
                v16 = tk ? ov : v16;
                i16 = tk ? oi : i16;
                x16 = tk ? ox : x16;
                y16 = tk ? oy : y16;
                z16 = tk ? oz : z16;
            }
            if (lane == 0) {
                int g = kk * PPB + i16;
                u64* sp = slot_ptr(slots, b, kk, s & 1);
                u64 tg = (u64)(unsigned)s << 32;
                u64 di = ((u64)(unsigned)s << 49)
                       | ((u64)__float_as_uint(v16) << 17)
                       | (u64)(unsigned)(131071 - g);
                __hip_atomic_store(sp + 0, tg | __float_as_uint(x16),
                                   __ATOMIC_RELAXED, __HIP_MEMORY_SCOPE_AGENT);
                __hip_atomic_store(sp + 1, tg | __float_as_uint(y16),
                                   __ATOMIC_RELAXED, __HIP_MEMORY_SCOPE_AGENT);
                __hip_atomic_store(sp + 2, tg | __float_as_uint(z16),
                                   __ATOMIC_RELAXED, __HIP_MEMORY_SCOPE_AGENT);
                __hip_atomic_store(sp + 3, di,
                                   __ATOMIC_RELAXED, __HIP_MEMORY_SCOPE_AGENT);
            }

            // wave 0 polls 8 blocks x 4 words (lanes 0..31), tag-matched
            u64 got = 0;
            if (lane < 32) {
                u64* ps = slot_ptr(slots, b, lane >> 2, s & 1) + (lane & 3);
                const int sh = ((lane & 3) == 3) ? 49 : 32;
                do {
                    got = __hip_atomic_load(ps, __ATOMIC_RELAXED,
                                            __HIP_MEMORY_SCOPE_AGENT);
                } while ((int)(got >> sh) != s);
            }
            // winner block by u64-max of di words (unique: idx in low bits)
            u64 dval = (u64)__shfl((long long)got, ((lane & 7) << 2) | 3);
            u64 dv = dval;
#pragma unroll
            for (int off = 1; off <= 4; off <<= 1) {
                u64 o = (u64)__shfl_xor((long long)dv, off);
                dv = (o > dv) ? o : dv;
            }
            u64 mask = __ballot(lane < 8 && dval == dv);
            int w = __ffsll((long long)mask) - 1;
            unsigned lo = (unsigned)got;
            unsigned cxb = (unsigned)__shfl((int)lo, w * 4 + 0);
            unsigned cyb = (unsigned)__shfl((int)lo, w * 4 + 1);
            unsigned czb = (unsigned)__shfl((int)lo, w * 4 + 2);
            if (lane == 0) {
                s_bc[0] = cxb; s_bc[1] = cyb; s_bc[2] = czb;
                if (kk == 0) out[(size_t)b * S + s] = 131071 - (int)(dv & 0x1FFFF);
            }
        }
        __syncthreads();   // barrier 2: result broadcast ready
        cx = __uint_as_float(s_bc[0]);
        cy = __uint_as_float(s_bc[1]);
        cz = __uint_as_float(s_bc[2]);
    }
}

extern "C" void kernel_launch(void* const* d_in, const int* in_sizes, int n_in,
                              void* d_out, int out_size, void* d_ws, size_t ws_size,
                              hipStream_t stream) {
    const float* points = (const float*)d_in[0];
    int* out   = (int*)d_out;
    u64* slots = (u64*)d_ws;              // 32*8*2*64B = 32 KB
    int S = out_size / NBATCH;            // 2048
    // 256 blocks x 16 waves -> exactly 1 block/CU on 256 CUs: co-resident.
    fps_kernel<<<dim3(NBATCH * KBLK), dim3(NTHR), 0, stream>>>(points, out, slots, S);
}

// Round 5
// 8521.120 us; speedup vs baseline: 1.0498x; 1.0498x over previous
//
#include <hip/hip_runtime.h>
#include <stdint.h>

typedef unsigned long long u64;

#define NBATCH 32
#define NPTS   131072
#define KBLK   8                 // blocks per batch
#define PPB    16384             // points per block (2^14)
#define NTHR   1024
#define NWAVE  16
#define PPT    16                // points per thread
#define FLT_MAX_C 3.402823466e+38f

// ws: per (batch, block, parity) one 64B slot of 8 u64.
// words 0..2: ((u64)s<<32) | float_bits(x|y|z)   -- self-tagged, relaxed
// word  3   : ((u64)s<<49) | dist_bits<<17 | (131071-gidx)
//   dist>=0 -> float bits monotone as uint; idx inverted so u64-max gives
//   first-occurrence argmax (np.argmax tie-break). 0xAA poison / stale tags
//   never equal live s -> no ws init needed; parity double-buffer + skew<=1:
//   a producer can only overwrite slot parity p at step s+2 after completing
//   step s+1, which requires every consumer to have published s+1, which
//   requires them to have finished reading step s. Proven safe in r2/r4 runs.
__device__ __forceinline__ u64* slot_ptr(u64* slots, int b, int k, int par) {
    return slots + ((size_t)((b * KBLK + k) * 2 + par)) * 8;
}

// waves_per_eu(4,4): pin the allocator's occupancy target to exactly 4
// waves/EU (16-wave block, 1 block/CU) so it uses the full 128-reg arch
// budget instead of a 64-VGPR-+-AGPR-shuttle split (r1/r2/r4 all showed
// VGPR_Count=64 with v_accvgpr traffic inflating VALU by ~2x).
__global__ __launch_bounds__(NTHR)
__attribute__((amdgpu_waves_per_eu(4, 4)))
void fps_kernel(const float* __restrict__ points, int* __restrict__ out,
                u64* __restrict__ slots, int S)
{
    const int b    = blockIdx.x & (NBATCH - 1);  // all 8 blocks of a batch
    const int kk   = blockIdx.x >> 5;            // share blockIdx%8 -> 1 XCD
    const int t    = threadIdx.x;
    const int lane = t & 63;
    const int wv   = t >> 6;

    const float* pb = points + (size_t)b * 3 * NPTS;
    const float* bx = pb + kk * PPB;
    const float* by = bx + NPTS;
    const float* bz = bx + 2 * NPTS;

    // 64 persistent floats per thread -- true VGPRs under the 128 budget.
    float px[PPT], py[PPT], pz[PPT], md[PPT];
    const int t4 = t * 4;
#pragma unroll
    for (int c = 0; c < 4; ++c) {
        float4 vx = *(const float4*)(bx + c * (NTHR * 4) + t4);
        float4 vy = *(const float4*)(by + c * (NTHR * 4) + t4);
        float4 vz = *(const float4*)(bz + c * (NTHR * 4) + t4);
        px[c*4+0]=vx.x; px[c*4+1]=vx.y; px[c*4+2]=vx.z; px[c*4+3]=vx.w;
        py[c*4+0]=vy.x; py[c*4+1]=vy.y; py[c*4+2]=vy.z; py[c*4+3]=vy.w;
        pz[c*4+0]=vz.x; pz[c*4+1]=vz.y; pz[c*4+2]=vz.z; pz[c*4+3]=vz.w;
        md[c*4+0]=FLT_MAX_C; md[c*4+1]=FLT_MAX_C;
        md[c*4+2]=FLT_MAX_C; md[c*4+3]=FLT_MAX_C;
    }

    __shared__ float s_pv[NWAVE], s_px[NWAVE], s_py[NWAVE], s_pz[NWAVE];
    __shared__ int   s_pi[NWAVE];
    __shared__ unsigned s_bc[3];

    float cx = pb[0], cy = pb[NPTS], cz = pb[2 * NPTS];
    if (kk == 0 && t == 0) out[(size_t)b * S] = 0;

    for (int s = 1; s < S; ++s) {
        // ---- scan: exact np fp32 semantics (no fma), ascending index, '>'
        float bv = -1.0f; int bp = 0;
        float bwx = 0.f, bwy = 0.f, bwz = 0.f;
#pragma unroll
        for (int p = 0; p < PPT; ++p) {
            float dx = __fsub_rn(px[p], cx);
            float dy = __fsub_rn(py[p], cy);
            float dz = __fsub_rn(pz[p], cz);
            float d  = __fadd_rn(__fadd_rn(__fmul_rn(dx, dx), __fmul_rn(dy, dy)),
                                 __fmul_rn(dz, dz));
            float m  = fminf(md[p], d);
            md[p] = m;
            bool tk = m > bv;
            bv  = tk ? m : bv;
            bp  = tk ? p : bp;          // inline-const cndmask
            bwx = tk ? px[p] : bwx;
            bwy = tk ? py[p] : bwy;
            bwz = tk ? pz[p] : bwz;
        }
        int gidx = kk * PPB + (bp >> 2) * (NTHR * 4) + t4 + (bp & 3);

        // ---- wave reduce carrying coords, tie -> lower index
#pragma unroll
        for (int off = 32; off >= 1; off >>= 1) {
            float ov = __shfl_down(bv, off);
            int   oi = __shfl_down(gidx, off);
            float ox = __shfl_down(bwx, off);
            float oy = __shfl_down(bwy, off);
            float oz = __shfl_down(bwz, off);
            bool tk = (ov > bv) || (ov == bv && oi < gidx);
            bv   = tk ? ov : bv;
            gidx = tk ? oi : gidx;
            bwx  = tk ? ox : bwx;
            bwy  = tk ? oy : bwy;
            bwz  = tk ? oz : bwz;
        }
        if (lane == 0) {
            s_pv[wv] = bv; s_pi[wv] = gidx;
            s_px[wv] = bwx; s_py[wv] = bwy; s_pz[wv] = bwz;
        }
        __syncthreads();   // barrier 1: partials ready

        if (wv == 0) {
            float v16 = (lane < NWAVE) ? s_pv[lane] : -1.0f;
            int   i16 = (lane < NWAVE) ? s_pi[lane] : 0x7fffffff;
            float x16 = (lane < NWAVE) ? s_px[lane] : 0.f;
            float y16 = (lane < NWAVE) ? s_py[lane] : 0.f;
            float z16 = (lane < NWAVE) ? s_pz[lane] : 0.f;
#pragma unroll
            for (int off = 8; off >= 1; off >>= 1) {
                float ov = __shfl_down(v16, off);
                int   oi = __shfl_down(i16, off);
                float ox = __shfl_down(x16, off);
                float oy = __shfl_down(y16, off);
                float oz = __shfl_down(z16, off);
                bool tk = (ov > v16) || (ov == v16 && oi < i16);
                v16 = tk ? ov : v16;
                i16 = tk ? oi : i16;
                x16 = tk ? ox : x16;
                y16 = tk ? oy : y16;
                z16 = tk ? oz : z16;
            }
            if (lane == 0) {
                u64* sp = slot_ptr(slots, b, kk, s & 1);
                u64 tg = (u64)(unsigned)s << 32;
                u64 di = ((u64)(unsigned)s << 49)
                       | ((u64)__float_as_uint(v16) << 17)
                       | (u64)(unsigned)(131071 - i16);
                __hip_atomic_store(sp + 0, tg | __float_as_uint(x16),
                                   __ATOMIC_RELAXED, __HIP_MEMORY_SCOPE_AGENT);
                __hip_atomic_store(sp + 1, tg | __float_as_uint(y16),
                                   __ATOMIC_RELAXED, __HIP_MEMORY_SCOPE_AGENT);
                __hip_atomic_store(sp + 2, tg | __float_as_uint(z16),
                                   __ATOMIC_RELAXED, __HIP_MEMORY_SCOPE_AGENT);
                __hip_atomic_store(sp + 3, di,
                                   __ATOMIC_RELAXED, __HIP_MEMORY_SCOPE_AGENT);
            }

            // wave 0 polls 8 blocks x 4 words (lanes 0..31), tag-matched
            u64 got = 0;
            if (lane < 32) {
                u64* ps = slot_ptr(slots, b, lane >> 2, s & 1) + (lane & 3);
                const int sh = ((lane & 3) == 3) ? 49 : 32;
                do {
                    got = __hip_atomic_load(ps, __ATOMIC_RELAXED,
                                            __HIP_MEMORY_SCOPE_AGENT);
                } while ((int)(got >> sh) != s);
            }
            // winner block by u64-max of di words (unique: idx in low bits)
            u64 dval = (u64)__shfl((long long)got, ((lane & 7) << 2) | 3);
            u64 dv = dval;
#pragma unroll
            for (int off = 1; off <= 4; off <<= 1) {
                u64 o = (u64)__shfl_xor((long long)dv, off);
                dv = (o > dv) ? o : dv;
            }
            u64 mask = __ballot(lane < 8 && dval == dv);
            int w = __ffsll((long long)mask) - 1;
            unsigned lo = (unsigned)got;
            unsigned cxb = (unsigned)__shfl((int)lo, w * 4 + 0);
            unsigned cyb = (unsigned)__shfl((int)lo, w * 4 + 1);
            unsigned czb = (unsigned)__shfl((int)lo, w * 4 + 2);
            if (lane == 0) {
                s_bc[0] = cxb; s_bc[1] = cyb; s_bc[2] = czb;
                if (kk == 0) out[(size_t)b * S + s] = 131071 - (int)(dv & 0x1FFFF);
            }
        }
        __syncthreads();   // barrier 2: result broadcast ready
        cx = __uint_as_float(s_bc[0]);
        cy = __uint_as_float(s_bc[1]);
        cz = __uint_as_float(s_bc[2]);
    }
}

extern "C" void kernel_launch(void* const* d_in, const int* in_sizes, int n_in,
                              void* d_out, int out_size, void* d_ws, size_t ws_size,
                              hipStream_t stream) {
    const float* points = (const float*)d_in[0];
    int* out   = (int*)d_out;
    u64* slots = (u64*)d_ws;              // 32*8*2*64B = 32 KB
    int S = out_size / NBATCH;            // 2048
    // 256 blocks x 16 waves -> exactly 1 block/CU on 256 CUs: co-resident.
    fps_kernel<<<dim3(NBATCH * KBLK), dim3(NTHR), 0, stream>>>(points, out, slots, S);
}

// Round 6
// 7132.009 us; speedup vs baseline: 1.2543x; 1.1948x over previous
//
#include <hip/hip_runtime.h>
#include <stdint.h>

typedef unsigned long long u64;

#define NBATCH 32
#define NPTS   131072
#define KBLK   8                 // blocks per batch
#define PPB    (NPTS / KBLK)     // 16384 points per block (2^14)
#define NTHR   1024
#define NWAVE  (NTHR / 64)       // 16 waves
#define PPT    (PPB / NTHR)      // 16 points per thread
#define FLT_MAX_C 3.402823466e+38f

// ws: per (batch, block, parity) one 64B slot of 8 u64.
// words 0..2: ((u64)s<<32) | float_bits(x|y|z)   -- self-tagged, relaxed
// word  3   : ((u64)s<<49) | dist_bits<<17 | (131071-idx)
//   dist>=0 -> float bits monotone as uint; idx inverted so u64-max gives
//   first-occurrence argmax (np.argmax tie-break). 0xAA poison / stale tags
//   never equal live s -> no ws init; parity double-buffer, skew<=1 proof.
__device__ __forceinline__ u64* slot_ptr(u64* slots, int b, int k, int par) {
    return slots + ((size_t)((b * KBLK + k) * 2 + par)) * 8;
}

__global__ __launch_bounds__(NTHR, 4)
void fps_kernel(const float* __restrict__ points, int* __restrict__ out,
                u64* __restrict__ slots, int S)
{
    const int b    = blockIdx.x & (NBATCH - 1);
    const int kk   = blockIdx.x >> 5;
    const int t    = threadIdx.x;
    const int lane = t & 63;
    const int wv   = t >> 6;

    const float* pb = points + (size_t)b * 3 * NPTS;
    const float* bx = pb + kk * PPB;
    const float* by = bx + NPTS;
    const float* bz = bx + 2 * NPTS;

    float px[PPT], py[PPT], pz[PPT], md[PPT];
    const int t4 = t * 4;
#pragma unroll
    for (int c = 0; c < PPT / 4; ++c) {
        float4 vx = *(const float4*)(bx + c * (NTHR * 4) + t4);
        float4 vy = *(const float4*)(by + c * (NTHR * 4) + t4);
        float4 vz = *(const float4*)(bz + c * (NTHR * 4) + t4);
        px[c*4+0]=vx.x; px[c*4+1]=vx.y; px[c*4+2]=vx.z; px[c*4+3]=vx.w;
        py[c*4+0]=vy.x; py[c*4+1]=vy.y; py[c*4+2]=vy.z; py[c*4+3]=vy.w;
        pz[c*4+0]=vz.x; pz[c*4+1]=vz.y; pz[c*4+2]=vz.z; pz[c*4+3]=vz.w;
        md[c*4+0]=FLT_MAX_C; md[c*4+1]=FLT_MAX_C;
        md[c*4+2]=FLT_MAX_C; md[c*4+3]=FLT_MAX_C;
    }
    // Pin the persistent state: values defined by volatile asm are opaque to
    // the allocator -- it cannot rematerialize them via global reloads inside
    // the scan (r1/r2/r4/r5 all showed VGPR_Count=64 + ~2x FETCH_SIZE: the
    // compiler was re-streaming px/py/pz from memory every step).
#pragma unroll
    for (int p = 0; p < PPT; ++p) {
        asm volatile("" : "+v"(px[p]), "+v"(py[p]), "+v"(pz[p]), "+v"(md[p]));
    }

    __shared__ float s_v[NWAVE];
    __shared__ int   s_i[NWAVE];
    __shared__ int   s_bi;          // block-winner idx (for owner extract)
    __shared__ unsigned s_bc[4];    // next centroid xbits,ybits,zbits,idx

    float cx = pb[0], cy = pb[NPTS], cz = pb[2 * NPTS];
    if (kk == 0 && t == 0) out[(size_t)b * S] = 0;

    for (int s = 1; s < S; ++s) {
        // ---- scan: exact np fp32 semantics (no fma), ascending-index '>'
        float bestv = -1.0f;
        int   bestp = 0;
#pragma unroll
        for (int p = 0; p < PPT; ++p) {
            float dx = __fsub_rn(px[p], cx);
            float dy = __fsub_rn(py[p], cy);
            float dz = __fsub_rn(pz[p], cz);
            float d  = __fadd_rn(__fadd_rn(__fmul_rn(dx, dx), __fmul_rn(dy, dy)),
                                 __fmul_rn(dz, dz));
            float m  = fminf(md[p], d);
            md[p] = m;
            bool tk = m > bestv;
            bestv = tk ? m : bestv;
            bestp = tk ? p : bestp;
        }
        int gidx = kk * PPB + (bestp >> 2) * (NTHR * 4) + t4 + (bestp & 3);

        // ---- wave reduce, tie -> lower index
#pragma unroll
        for (int off = 32; off >= 1; off >>= 1) {
            float ov = __shfl_down(bestv, off);
            int   oi = __shfl_down(gidx, off);
            bool tk = (ov > bestv) || (ov == bestv && oi < gidx);
            bestv = tk ? ov : bestv;
            gidx  = tk ? oi : gidx;
        }
        if (lane == 0) { s_v[wv] = bestv; s_i[wv] = gidx; }
        __syncthreads();

        // ---- cross-wave reduce in wave 0; publish di word (relaxed)
        if (wv == 0) {
            float v16 = (lane < NWAVE) ? s_v[lane] : -1.0f;
            int   i16 = (lane < NWAVE) ? s_i[lane] : 0x7fffffff;
#pragma unroll
            for (int off = 8; off >= 1; off >>= 1) {
                float ov = __shfl_down(v16, off);
                int   oi = __shfl_down(i16, off);
                bool tk = (ov > v16) || (ov == v16 && oi < i16);
                v16 = tk ? ov : v16;
                i16 = tk ? oi : i16;
            }
            if (lane == 0) {
                u64 di = ((u64)(unsigned)s << 49)
                       | ((u64)__float_as_uint(v16) << 17)
                       | (u64)(unsigned)(131071 - i16);
                __hip_atomic_store(slot_ptr(slots, b, kk, s & 1) + 3, di,
                                   __ATOMIC_RELAXED, __HIP_MEMORY_SCOPE_AGENT);
                s_bi = i16;
            }
        }
        __syncthreads();

        // ---- owner thread ships the block-winner coords (self-tagged words)
        int widx = s_bi;
        if ((widx >> 14) == kk) {
            int l = widx & (PPB - 1);
            if (t == ((l >> 2) & (NTHR - 1))) {
                int pw = ((l >> 12) << 2) | (l & 3);   // c*4 + j
                float wx = 0.f, wy = 0.f, wz = 0.f;
#pragma unroll
                for (int p = 0; p < PPT; ++p) {        // constant-index select
                    bool e = (p == pw);
                    wx = e ? px[p] : wx; wy = e ? py[p] : wy; wz = e ? pz[p] : wz;
                }
                u64 tg = (u64)(unsigned)s << 32;
                u64* sp = slot_ptr(slots, b, kk, s & 1);
                __hip_atomic_store(sp + 0, tg | __float_as_uint(wx),
                                   __ATOMIC_RELAXED, __HIP_MEMORY_SCOPE_AGENT);
                __hip_atomic_store(sp + 1, tg | __float_as_uint(wy),
                                   __ATOMIC_RELAXED, __HIP_MEMORY_SCOPE_AGENT);
                __hip_atomic_store(sp + 2, tg | __float_as_uint(wz),
                                   __ATOMIC_RELAXED, __HIP_MEMORY_SCOPE_AGENT);
            }
        }

        // ---- wave 0: poll all 8 blocks' 4 words (relaxed, tag-matched)
        if (wv == 0) {
            u64 got = 0;
            if (lane < 32) {
                u64* ps = slot_ptr(slots, b, lane >> 2, s & 1) + (lane & 3);
                const int sh = ((lane & 3) == 3) ? 49 : 32;
                do {
                    got = __hip_atomic_load(ps, __ATOMIC_RELAXED,
                                            __HIP_MEMORY_SCOPE_AGENT);
                } while ((int)(got >> sh) != s);
            }
            // select winning block by u64-max of di words (unique: idx low bits)
            u64 dval = (u64)__shfl((long long)got, lane * 4 + 3);
            u64 dv = (lane < 8) ? dval : 0ull;
#pragma unroll
            for (int off = 4; off >= 1; off >>= 1) {
                u64 o = (u64)__shfl_down((long long)dv, off);
                dv = (o > dv) ? o : dv;
            }
            u64 win = (u64)__shfl((long long)dv, 0);
            u64 mask = __ballot(lane < 8 && dval == win);
            int w = __ffsll(mask) - 1;
            unsigned lo = (unsigned)got;
            unsigned cxb = (unsigned)__shfl((int)lo, w * 4 + 0);
            unsigned cyb = (unsigned)__shfl((int)lo, w * 4 + 1);
            unsigned czb = (unsigned)__shfl((int)lo, w * 4 + 2);
            int idx = 131071 - (int)(win & 0x1FFFF);
            if (lane == 0) {
                s_bc[0] = cxb; s_bc[1] = cyb; s_bc[2] = czb; s_bc[3] = (unsigned)idx;
                if (kk == 0) out[(size_t)b * S + s] = idx;
            }
        }
        __syncthreads();
        cx = __uint_as_float(s_bc[0]);
        cy = __uint_as_float(s_bc[1]);
        cz = __uint_as_float(s_bc[2]);
    }
}

extern "C" void kernel_launch(void* const* d_in, const int* in_sizes, int n_in,
                              void* d_out, int out_size, void* d_ws, size_t ws_size,
                              hipStream_t stream) {
    const float* points = (const float*)d_in[0];
    int* out   = (int*)d_out;
    u64* slots = (u64*)d_ws;              // 32*8*2*64B = 32 KB
    int S = out_size / NBATCH;            // 2048
    // 256 blocks x 16 waves -> exactly 1 block/CU on 256 CUs: co-resident.
    fps_kernel<<<dim3(NBATCH * KBLK), dim3(NTHR), 0, stream>>>(points, out, slots, S);
}